// Round 2
// baseline (555.559 us; speedup 1.0000x reference)
//
#include <hip/hip_runtime.h>
#include <hip/hip_bf16.h>

// EdgeApplyModule: out[e] = relu(concat(node[src[e]], edge[e], node[dst[e]]) @ W + b)
// N_EDGES=1e6, D_NODE=D_EDGE=D_OUT=64, D_IN=192. All f32 in/out; bf16 MFMA compute.

typedef __attribute__((ext_vector_type(8))) short short8;
typedef __attribute__((ext_vector_type(4))) float f32x4;

#define D 64
#define DIN 192
#define BM 64   // edges per block

__device__ __forceinline__ short bf_bits(float f) {
  __hip_bfloat16 h = __float2bfloat16(f);  // RNE
  union { __hip_bfloat16 b; short s; } u; u.b = h;
  return u.s;
}

// Pre-arrange W (f32 [192][64] row-major) into bf16 MFMA B-fragment layout in d_ws:
// wsB[((t*4 + c)*64 + l)*8 + s] = bf16(W[32t + (l>>4)*8 + s][16c + (l&15)])
// t = k-step (0..5), c = col-tile (0..3), l = lane (0..63), s = slot (0..7).
__global__ void prep_W_kernel(const float* __restrict__ W,
                              unsigned short* __restrict__ wsB) {
  int i = blockIdx.x * blockDim.x + threadIdx.x;
  if (i >= DIN * D) return;
  int k = i >> 6;          // 0..191
  int n = i & 63;          // 0..63
  int t = k >> 5;
  int g = (k >> 3) & 3;
  int s = k & 7;
  int c = n >> 4;
  int l = g * 16 + (n & 15);
  wsB[(((t << 2) + c) * 64 + l) * 8 + s] = (unsigned short)bf_bits(W[i]);
}

__global__ __launch_bounds__(256) void edge_mlp_kernel(
    const float* __restrict__ node_feat,   // [100000][64]
    const float* __restrict__ edge_feat,   // [1e6][64]
    const int*   __restrict__ src_idx,     // [1e6]
    const int*   __restrict__ dst_idx,     // [1e6]
    const unsigned short* __restrict__ wsB,// [6][4][64][8] bf16 bits
    const float* __restrict__ bias,        // [64]
    float* __restrict__ out,               // [1e6][64]
    int nE) {
  const int tid = threadIdx.x;
  const int w = tid >> 6;       // wave 0..3
  const int l = tid & 63;       // lane
  const int g = l >> 4;         // k-group 0..3
  const int r = l & 15;         // A-row / B-col within tile

  const long base = (long)blockIdx.x * BM + w * 16;
  int e = (int)base + r;
  int eL = e < nE ? e : nE - 1;  // clamp (exact divide in practice)

  const int si = src_idx[eL];
  const int di = dst_idx[eL];
  const float* pSrc = node_feat + (size_t)si * D;
  const float* pEdg = edge_feat + (size_t)eL * D;
  const float* pDst = node_feat + (size_t)di * D;

  f32x4 acc0 = {0.f, 0.f, 0.f, 0.f};
  f32x4 acc1 = {0.f, 0.f, 0.f, 0.f};
  f32x4 acc2 = {0.f, 0.f, 0.f, 0.f};
  f32x4 acc3 = {0.f, 0.f, 0.f, 0.f};

  const short8* B = reinterpret_cast<const short8*>(wsB);

  #pragma unroll
  for (int t = 0; t < 6; ++t) {
    const float* seg = (t < 2) ? pSrc : (t < 4) ? pEdg : pDst;
    const float* p = seg + (t & 1) * 32 + g * 8;
    float4 x = *reinterpret_cast<const float4*>(p);
    float4 y = *reinterpret_cast<const float4*>(p + 4);
    short8 a;
    a[0] = bf_bits(x.x); a[1] = bf_bits(x.y);
    a[2] = bf_bits(x.z); a[3] = bf_bits(x.w);
    a[4] = bf_bits(y.x); a[5] = bf_bits(y.y);
    a[6] = bf_bits(y.z); a[7] = bf_bits(y.w);

    short8 b0 = B[(t * 4 + 0) * 64 + l];
    short8 b1 = B[(t * 4 + 1) * 64 + l];
    short8 b2 = B[(t * 4 + 2) * 64 + l];
    short8 b3 = B[(t * 4 + 3) * 64 + l];
    acc0 = __builtin_amdgcn_mfma_f32_16x16x32_bf16(a, b0, acc0, 0, 0, 0);
    acc1 = __builtin_amdgcn_mfma_f32_16x16x32_bf16(a, b1, acc1, 0, 0, 0);
    acc2 = __builtin_amdgcn_mfma_f32_16x16x32_bf16(a, b2, acc2, 0, 0, 0);
    acc3 = __builtin_amdgcn_mfma_f32_16x16x32_bf16(a, b3, acc3, 0, 0, 0);
  }

  // Epilogue: C/D layout col = lane&15, row = (lane>>4)*4 + reg  [m89-verified]
  f32x4 accs[4] = {acc0, acc1, acc2, acc3};
  #pragma unroll
  for (int c = 0; c < 4; ++c) {
    const int n = c * 16 + r;
    const float bn = bias[n];
    #pragma unroll
    for (int j = 0; j < 4; ++j) {
      const long eo = base + g * 4 + j;
      if (eo < nE) {
        float v = accs[c][j] + bn;
        out[eo * D + n] = v > 0.f ? v : 0.f;
      }
    }
  }
}

extern "C" void kernel_launch(void* const* d_in, const int* in_sizes, int n_in,
                              void* d_out, int out_size, void* d_ws, size_t ws_size,
                              hipStream_t stream) {
  const float* node_feat = (const float*)d_in[0];
  const float* edge_feat = (const float*)d_in[1];
  const int*   src_idx   = (const int*)d_in[2];
  const int*   dst_idx   = (const int*)d_in[3];
  const float* W         = (const float*)d_in[4];
  const float* bias      = (const float*)d_in[5];
  float* out = (float*)d_out;
  unsigned short* wsB = (unsigned short*)d_ws;  // needs 6*4*64*8*2 = 24576 B

  const int nE = in_sizes[2];  // 1,000,000

  hipLaunchKernelGGL(prep_W_kernel, dim3((DIN * D + 255) / 256), dim3(256), 0,
                     stream, W, wsB);

  const int nBlocks = (nE + BM - 1) / BM;  // 15625
  hipLaunchKernelGGL(edge_mlp_kernel, dim3(nBlocks), dim3(256), 0, stream,
                     node_feat, edge_feat, src_idx, dst_idx, wsB, bias, out, nE);
}

// Round 4
// 499.619 us; speedup vs baseline: 1.1120x; 1.1120x over previous
//
#include <hip/hip_runtime.h>
#include <hip/hip_bf16.h>

// EdgeApplyModule: out[e] = relu(concat(node[src[e]], edge[e], node[dst[e]]) @ W + b)
// N_EDGES=1e6, D_NODE=D_EDGE=D_OUT=64, D_IN=192. f32 in/out; bf16 MFMA compute.
//
// R2: grid-stride (grid=2048) to fix workgroup-dispatch-bound regime seen in R1
// (15625 tiny blocks @ 15.7 ns/block, all pipes <10%). wsB stays L1-hot across
// iterations; bias hoisted.

typedef __attribute__((ext_vector_type(8))) short short8;
typedef __attribute__((ext_vector_type(4))) float f32x4;

#define D 64
#define DIN 192
#define BM 64      // edges per chunk
#define GRID 2048  // ~8 blocks/CU, grid-stride over 15625 chunks

__device__ __forceinline__ short bf_bits(float f) {
  __hip_bfloat16 h = __float2bfloat16(f);  // RNE
  union { __hip_bfloat16 b; short s; } u; u.b = h;
  return u.s;
}

// Pre-arrange W (f32 [192][64] row-major) into bf16 MFMA B-fragment layout in d_ws:
// wsB[((t*4 + c)*64 + l)*8 + s] = bf16(W[32t + (l>>4)*8 + s][16c + (l&15)])
__global__ void prep_W_kernel(const float* __restrict__ W,
                              unsigned short* __restrict__ wsB) {
  int i = blockIdx.x * blockDim.x + threadIdx.x;
  if (i >= DIN * D) return;
  int k = i >> 6;          // 0..191
  int n = i & 63;          // 0..63
  int t = k >> 5;
  int g = (k >> 3) & 3;
  int s = k & 7;
  int c = n >> 4;
  int l = g * 16 + (n & 15);
  wsB[(((t << 2) + c) * 64 + l) * 8 + s] = (unsigned short)bf_bits(W[i]);
}

__global__ __launch_bounds__(256) void edge_mlp_kernel(
    const float* __restrict__ node_feat,   // [100000][64]
    const float* __restrict__ edge_feat,   // [1e6][64]
    const int*   __restrict__ src_idx,     // [1e6]
    const int*   __restrict__ dst_idx,     // [1e6]
    const unsigned short* __restrict__ wsB,// [6][4][64][8] bf16 bits
    const float* __restrict__ bias,        // [64]
    float* __restrict__ out,               // [1e6][64]
    int nE) {
  const int tid = threadIdx.x;
  const int w = tid >> 6;       // wave 0..3
  const int l = tid & 63;       // lane
  const int g = l >> 4;         // k-group 0..3
  const int r = l & 15;         // A-row / B-col within tile

  const short8* B = reinterpret_cast<const short8*>(wsB);

  // bias for this lane's 4 output columns — loop-invariant
  float bn0 = bias[0 * 16 + r];
  float bn1 = bias[1 * 16 + r];
  float bn2 = bias[2 * 16 + r];
  float bn3 = bias[3 * 16 + r];

  const int nChunks = (nE + BM - 1) / BM;  // 15625

  for (int chunk = blockIdx.x; chunk < nChunks; chunk += gridDim.x) {
    const long base = (long)chunk * BM + w * 16;
    int e = (int)base + r;
    int eL = e < nE ? e : nE - 1;  // clamp (exact divide in practice)

    const int si = src_idx[eL];
    const int di = dst_idx[eL];
    const float* pSrc = node_feat + (size_t)si * D;
    const float* pEdg = edge_feat + (size_t)eL * D;
    const float* pDst = node_feat + (size_t)di * D;

    f32x4 acc0 = {0.f, 0.f, 0.f, 0.f};
    f32x4 acc1 = {0.f, 0.f, 0.f, 0.f};
    f32x4 acc2 = {0.f, 0.f, 0.f, 0.f};
    f32x4 acc3 = {0.f, 0.f, 0.f, 0.f};

    #pragma unroll
    for (int t = 0; t < 6; ++t) {
      const float* seg = (t < 2) ? pSrc : (t < 4) ? pEdg : pDst;
      const float* p = seg + (t & 1) * 32 + g * 8;
      float4 x = *reinterpret_cast<const float4*>(p);
      float4 y = *reinterpret_cast<const float4*>(p + 4);
      short8 a;
      a[0] = bf_bits(x.x); a[1] = bf_bits(x.y);
      a[2] = bf_bits(x.z); a[3] = bf_bits(x.w);
      a[4] = bf_bits(y.x); a[5] = bf_bits(y.y);
      a[6] = bf_bits(y.z); a[7] = bf_bits(y.w);

      short8 b0 = B[(t * 4 + 0) * 64 + l];  // L1-hot after first chunk
      short8 b1 = B[(t * 4 + 1) * 64 + l];
      short8 b2 = B[(t * 4 + 2) * 64 + l];
      short8 b3 = B[(t * 4 + 3) * 64 + l];
      acc0 = __builtin_amdgcn_mfma_f32_16x16x32_bf16(a, b0, acc0, 0, 0, 0);
      acc1 = __builtin_amdgcn_mfma_f32_16x16x32_bf16(a, b1, acc1, 0, 0, 0);
      acc2 = __builtin_amdgcn_mfma_f32_16x16x32_bf16(a, b2, acc2, 0, 0, 0);
      acc3 = __builtin_amdgcn_mfma_f32_16x16x32_bf16(a, b3, acc3, 0, 0, 0);
    }

    // C/D layout: col = lane&15, row = (lane>>4)*4 + reg  [m89-verified]
    f32x4 accs[4] = {acc0, acc1, acc2, acc3};
    float bns[4] = {bn0, bn1, bn2, bn3};
    #pragma unroll
    for (int c = 0; c < 4; ++c) {
      const int n = c * 16 + r;
      #pragma unroll
      for (int j = 0; j < 4; ++j) {
        const long eo = base + g * 4 + j;
        if (eo < nE) {
          float v = accs[c][j] + bns[c];
          out[eo * D + n] = v > 0.f ? v : 0.f;
        }
      }
    }
  }
}

extern "C" void kernel_launch(void* const* d_in, const int* in_sizes, int n_in,
                              void* d_out, int out_size, void* d_ws, size_t ws_size,
                              hipStream_t stream) {
  const float* node_feat = (const float*)d_in[0];
  const float* edge_feat = (const float*)d_in[1];
  const int*   src_idx   = (const int*)d_in[2];
  const int*   dst_idx   = (const int*)d_in[3];
  const float* W         = (const float*)d_in[4];
  const float* bias      = (const float*)d_in[5];
  float* out = (float*)d_out;
  unsigned short* wsB = (unsigned short*)d_ws;  // needs 6*4*64*8*2 = 24576 B

  const int nE = in_sizes[2];  // 1,000,000

  hipLaunchKernelGGL(prep_W_kernel, dim3((DIN * D + 255) / 256), dim3(256), 0,
                     stream, W, wsB);

  const int nChunks = (nE + BM - 1) / BM;  // 15625
  const int grid = nChunks < GRID ? nChunks : GRID;
  hipLaunchKernelGGL(edge_mlp_kernel, dim3(grid), dim3(256), 0, stream,
                     node_feat, edge_feat, src_idx, dst_idx, wsB, bias, out, nE);
}